// Round 10
// baseline (373.547 us; speedup 1.0000x reference)
//
#include <hip/hip_runtime.h>
#include <hip/hip_bf16.h>

// EmbeddingRNN via MFMA, round 10 = R9 (144us, zero-spill) + L2-queue hygiene:
//  (1) raw barrier: s_waitcnt lgkmcnt(0) + s_barrier instead of __syncthreads()
//      -> the per-step vmcnt(0) drain goes away; B loads stay in flight across
//      the step boundary (only LDS h-publication needs the barrier).
//  (2) next step's kt=0 B-frags prefetched BEFORE the barrier (warm queue).
//  (3) 3-deep B rotation (bA/bB/bC): load-ahead = 2 MFMA clusters (~160-320cy)
//      > L2-hit latency (~200cy) -> B latency fully hidden in steady state.
// Register budget: acc 64 + 48 B-frags + addressing ~124 <= 128 cap.
// WRITE_SIZE == 8.2MB(out) is the spill-meter; >8.2MB = abort signal.

#define DD      256
#define G4      1024
#define NCHAR   155
#define TSTEPS  16
#define RTILE   32
#define NROWS   8192
#define NBLOCKS (NROWS / RTILE)   // 256
#define NTHREADS 512              // 8 waves; wave w owns d-slice [w*32, w*32+32)

typedef __attribute__((ext_vector_type(8))) short bf16x8;
typedef __attribute__((ext_vector_type(4))) float f32x4;

__device__ inline unsigned short f2bf_bits(float f) {
    __hip_bfloat16 h = __float2bfloat16(f);   // RTNE
    return *reinterpret_cast<unsigned short*>(&h);
}

__device__ inline float sigmoid_fast(float x) {
    return __builtin_amdgcn_rcpf(1.f + __expf(-x));
}

// ---------------- phase 0a: embWp = pack(emb @ W + b) ----------------
// value (char i, gate g, col d): w=d>>5, l15=d&15, nn=(d>>4)&1, nt=g*2+nn
// embWp[ ((i*8 + w)*16 + l15)*8 + nt ]
__global__ __launch_bounds__(256)
void embw_kernel(const float* __restrict__ emb, const float* __restrict__ W,
                 const float* __restrict__ b, float* __restrict__ embWp) {
    const int i   = blockIdx.x;
    const int tid = threadIdx.x;
    float a0 = b[tid], a1 = b[256 + tid], a2 = b[512 + tid], a3 = b[768 + tid];
    const float* er = emb + i * DD;
    for (int k = 0; k < DD; ++k) {
        const float e = er[k];
        const float* wr = W + k * G4 + tid;
        a0 += e * wr[0];
        a1 += e * wr[256];
        a2 += e * wr[512];
        a3 += e * wr[768];
    }
    const int w = tid >> 5, l15 = tid & 15, nn = (tid >> 4) & 1;
    float* o = embWp + ((i * 8 + w) * 16 + l15) * 8 + nn;
    o[0] = a0; o[2] = a1; o[4] = a2; o[6] = a3;   // nt = g*2+nn
}

// ---------------- phase 0b: pack U into bf16 MFMA B-fragments ----------------
// up[((w*8 + kt)*8 + nt)*64 + lane]: lane l holds
//   U[kt*32+(l>>4)*8+j][g*256 + w*32 + nn*16 + (l&15)], nt=g*2+nn
__global__ __launch_bounds__(256)
void upack_kernel(const float* __restrict__ U, bf16x8* __restrict__ up) {
    const int gid  = blockIdx.x * 256 + threadIdx.x;   // 32768 total
    const int lane = gid & 63;
    const int nt   = (gid >> 6) & 7;
    const int kt   = (gid >> 9) & 7;
    const int w    = gid >> 12;
    const int g = nt >> 1, nn = nt & 1;
    const int col = g * 256 + w * 32 + nn * 16 + (lane & 15);
    const int k0  = kt * 32 + (lane >> 4) * 8;
    bf16x8 v;
#pragma unroll
    for (int j = 0; j < 8; ++j) v[j] = (short)f2bf_bits(U[(k0 + j) * G4 + col]);
    up[gid] = v;
}

// ---------------- phase 1: fused recurrence ----------------

#define LOADB(DST, KT)                                                          \
    _Pragma("unroll")                                                           \
    for (int nt = 0; nt < 8; ++nt) (DST)[nt] = upw[((KT) * 8 + nt) * 64 + lane];

// A-frags for K-tile KT from swizzled bf16 LDS, then 16 MFMAs
#define AFR_MFMA(KT, BARR)                                                      \
    {                                                                           \
        const int kb = ((KT) * 32 + lg * 8) * 2;                                \
        const int r0 = l15, r1 = 16 + l15;                                      \
        bf16x8 afr0 = *(const bf16x8*)(rbb + ((r0 * 512 + kb) ^ ((r0 & 7) << 4))); \
        bf16x8 afr1 = *(const bf16x8*)(rbb + ((r1 * 512 + kb) ^ ((r1 & 7) << 4))); \
        _Pragma("unroll")                                                       \
        for (int nt = 0; nt < 8; ++nt) {                                        \
            acc[0][nt] = __builtin_amdgcn_mfma_f32_16x16x32_bf16(               \
                afr0, (BARR)[nt], acc[0][nt], 0, 0, 0);                         \
            acc[1][nt] = __builtin_amdgcn_mfma_f32_16x16x32_bf16(               \
                afr1, (BARR)[nt], acc[1][nt], 0, 0, 0);                         \
        }                                                                       \
    }

__global__ __launch_bounds__(NTHREADS)
void lstm_mfma(const int* __restrict__ x, const float* __restrict__ embWp,
               const bf16x8* __restrict__ up, float* __restrict__ out) {
    // h: bf16, double buffer, byte-swizzle ^((row&7)<<4), 1 raw barrier/step.
    // c: f32 in LDS, stride 257 (thread-private slots, no sync needed).
    __shared__ __align__(16) unsigned short hb[2][RTILE * DD];  // 32KB
    __shared__ float cb[RTILE * 257];                           // ~33KB
    __shared__ int   xs[RTILE * TSTEPS];                        // 2KB

    const int tid  = threadIdx.x;
    const int w    = tid >> 6;
    const int lane = tid & 63;
    const int l15  = lane & 15, lg = lane >> 4;
    const int base = blockIdx.x * RTILE;

    xs[tid] = x[base * TSTEPS + tid];

    f32x4 acc[2][8];          // 64 accumulator regs
    bf16x8 bA[8], bB[8], bC[8];   // 48 B-frag regs, rotation

    // zero this thread's 16 c-slots
#pragma unroll
    for (int mt = 0; mt < 2; ++mt)
#pragma unroll
        for (int nn = 0; nn < 2; ++nn)
#pragma unroll
            for (int j = 0; j < 4; ++j)
                cb[(mt * 16 + lg * 4 + j) * 257 + w * 32 + nn * 16 + l15] = 0.f;

    const bf16x8* upw = up + w * 4096;    // this wave's 64KB packed U slice

    __syncthreads();   // init barrier (full drain fine here, once)

#pragma unroll 1
    for (int t = 0; t < TSTEPS; ++t) {
        // ---- acc init: z = embW[x_t] gather (+b folded), 2 float4/(mt,j) ----
#pragma unroll
        for (int mt = 0; mt < 2; ++mt) {
#pragma unroll
            for (int j = 0; j < 4; ++j) {
                const int r    = mt * 16 + lg * 4 + j;        // C/D row
                const int xrow = xs[r * TSTEPS + t];
                const float4* ew =
                    (const float4*)(embWp + ((xrow * 8 + w) * 16 + l15) * 8);
                const float4 g0 = ew[0];
                const float4 g1 = ew[1];
                acc[mt][0][j] = g0.x; acc[mt][1][j] = g0.y;
                acc[mt][2][j] = g0.z; acc[mt][3][j] = g0.w;
                acc[mt][4][j] = g1.x; acc[mt][5][j] = g1.y;
                acc[mt][6][j] = g1.z; acc[mt][7][j] = g1.w;
            }
        }

        // ---- z += h @ U via MFMA; 3-deep rotation, bA pre-loaded last step ----
        if (t > 0) {
            const char* rbb = (const char*)hb[(t - 1) & 1];
            LOADB(bB, 1) LOADB(bC, 2)
            AFR_MFMA(0, bA) LOADB(bA, 3)
            AFR_MFMA(1, bB) LOADB(bB, 4)
            AFR_MFMA(2, bC) LOADB(bC, 5)
            AFR_MFMA(3, bA) LOADB(bA, 6)
            AFR_MFMA(4, bB) LOADB(bB, 7)
            AFR_MFMA(5, bC)
            AFR_MFMA(6, bA)
            AFR_MFMA(7, bB)
        }

        // ---- prefetch next step's kt=0 B-frags (stay in flight across barrier) ----
        if (t < TSTEPS - 1) { LOADB(bA, 0) }

        // ---- gate update (Keras i,f,g,o; identity candidate/output) ----
        {
            char* wbb = (char*)hb[t & 1];
#pragma unroll
            for (int mt = 0; mt < 2; ++mt) {
#pragma unroll
                for (int nn = 0; nn < 2; ++nn) {
#pragma unroll
                    for (int j = 0; j < 4; ++j) {
                        const float zi = acc[mt][0 + nn][j];
                        const float zf = acc[mt][2 + nn][j];
                        const float zg = acc[mt][4 + nn][j];
                        const float zo = acc[mt][6 + nn][j];
                        const float ig = sigmoid_fast(zi);
                        const float fg = sigmoid_fast(zf);
                        const float og = sigmoid_fast(zo);
                        const int row = mt * 16 + lg * 4 + j;
                        const int d   = w * 32 + nn * 16 + l15;
                        float* cp = &cb[row * 257 + d];
                        const float cn = fg * (*cp) + ig * zg;
                        *cp = cn;
                        const float h = og * cn;
                        *(unsigned short*)(wbb +
                            ((row * 512 + d * 2) ^ ((row & 7) << 4))) = f2bf_bits(h);
                        if (t == TSTEPS - 1) out[(base + row) * DD + d] = h;
                    }
                }
            }
        }

        // ---- raw barrier: publish h(t) via LDS; do NOT drain vmcnt ----
        asm volatile("s_waitcnt lgkmcnt(0)" ::: "memory");
        __builtin_amdgcn_s_barrier();
    }
}

extern "C" void kernel_launch(void* const* d_in, const int* in_sizes, int n_in,
                              void* d_out, int out_size, void* d_ws, size_t ws_size,
                              hipStream_t stream) {
    const int*   x   = (const int*)d_in[0];
    const float* emb = (const float*)d_in[1];
    const float* W   = (const float*)d_in[2];
    const float* U   = (const float*)d_in[3];
    const float* b   = (const float*)d_in[4];
    float* out = (float*)d_out;

    float*  embWp = (float*)d_ws;                          // 620KB
    bf16x8* up    = (bf16x8*)((char*)d_ws + (1 << 20));    // 512KB at +1MB

    embw_kernel<<<NCHAR, 256, 0, stream>>>(emb, W, b, embWp);
    upack_kernel<<<128, 256, 0, stream>>>(U, up);
    lstm_mfma<<<NBLOCKS, NTHREADS, 0, stream>>>(x, embWp, up, out);
}

// Round 11
// 154.487 us; speedup vs baseline: 2.4180x; 2.4180x over previous
//
#include <hip/hip_runtime.h>
#include <hip/hip_bf16.h>

// EmbeddingRNN via MFMA, round 11 = R9 chassis (144us, zero-spill, VGPR 100)
// + the register-free subset of R10's queue hygiene:
//  (1) raw barrier (s_waitcnt lgkmcnt(0); s_barrier in ONE asm, memory clobber)
//      -> no vmcnt(0) drain at step boundaries; global B loads may cross.
//  (2) kt=0 B-frags for step t+1 prefetched during step t's gate phase, i.e.
//      BEFORE the barrier -> MFMA pipeline opens warm each step.
//  (3) kt pipeline kept ROLLED exactly as R9 (the proven-spill-free shape);
//      bA/bB hoisted to function scope, net register delta ~0.
// R10 lesson: +16 persistent regs (bC) -> 128-cap spill (WRITE 54.9MB). The
// spill-meter (WRITE_SIZE == 8.2MB == out) gates this round.

#define DD      256
#define G4      1024
#define NCHAR   155
#define TSTEPS  16
#define RTILE   32
#define NROWS   8192
#define NBLOCKS (NROWS / RTILE)   // 256
#define NTHREADS 512              // 8 waves; wave w owns d-slice [w*32, w*32+32)

typedef __attribute__((ext_vector_type(8))) short bf16x8;
typedef __attribute__((ext_vector_type(4))) float f32x4;

__device__ inline unsigned short f2bf_bits(float f) {
    __hip_bfloat16 h = __float2bfloat16(f);   // RTNE
    return *reinterpret_cast<unsigned short*>(&h);
}

__device__ inline float sigmoid_fast(float x) {
    return __builtin_amdgcn_rcpf(1.f + __expf(-x));
}

// ---------------- phase 0a: embWp = pack(emb @ W + b) ----------------
// value (char i, gate g, col d): w=d>>5, l15=d&15, nn=(d>>4)&1, nt=g*2+nn
// embWp[ ((i*8 + w)*16 + l15)*8 + nt ]
__global__ __launch_bounds__(256)
void embw_kernel(const float* __restrict__ emb, const float* __restrict__ W,
                 const float* __restrict__ b, float* __restrict__ embWp) {
    const int i   = blockIdx.x;
    const int tid = threadIdx.x;
    float a0 = b[tid], a1 = b[256 + tid], a2 = b[512 + tid], a3 = b[768 + tid];
    const float* er = emb + i * DD;
    for (int k = 0; k < DD; ++k) {
        const float e = er[k];
        const float* wr = W + k * G4 + tid;
        a0 += e * wr[0];
        a1 += e * wr[256];
        a2 += e * wr[512];
        a3 += e * wr[768];
    }
    const int w = tid >> 5, l15 = tid & 15, nn = (tid >> 4) & 1;
    float* o = embWp + ((i * 8 + w) * 16 + l15) * 8 + nn;
    o[0] = a0; o[2] = a1; o[4] = a2; o[6] = a3;   // nt = g*2+nn
}

// ---------------- phase 0b: pack U into bf16 MFMA B-fragments ----------------
// up[((w*8 + kt)*8 + nt)*64 + lane]: lane l holds
//   U[kt*32+(l>>4)*8+j][g*256 + w*32 + nn*16 + (l&15)], nt=g*2+nn
__global__ __launch_bounds__(256)
void upack_kernel(const float* __restrict__ U, bf16x8* __restrict__ up) {
    const int gid  = blockIdx.x * 256 + threadIdx.x;   // 32768 total
    const int lane = gid & 63;
    const int nt   = (gid >> 6) & 7;
    const int kt   = (gid >> 9) & 7;
    const int w    = gid >> 12;
    const int g = nt >> 1, nn = nt & 1;
    const int col = g * 256 + w * 32 + nn * 16 + (lane & 15);
    const int k0  = kt * 32 + (lane >> 4) * 8;
    bf16x8 v;
#pragma unroll
    for (int j = 0; j < 8; ++j) v[j] = (short)f2bf_bits(U[(k0 + j) * G4 + col]);
    up[gid] = v;
}

// ---------------- phase 1: fused recurrence ----------------

#define LOADB(DST, KT)                                                          \
    _Pragma("unroll")                                                           \
    for (int nt = 0; nt < 8; ++nt) (DST)[nt] = upw[((KT) * 8 + nt) * 64 + lane];

// A-frags for (runtime) K-tile KT from swizzled bf16 LDS, then 16 MFMAs
#define AFR_MFMA(KT, BARR)                                                      \
    {                                                                           \
        const int kb = ((KT) * 32 + lg * 8) * 2;                                \
        const int r0 = l15, r1 = 16 + l15;                                      \
        bf16x8 afr0 = *(const bf16x8*)(rbb + ((r0 * 512 + kb) ^ ((r0 & 7) << 4))); \
        bf16x8 afr1 = *(const bf16x8*)(rbb + ((r1 * 512 + kb) ^ ((r1 & 7) << 4))); \
        _Pragma("unroll")                                                       \
        for (int nt = 0; nt < 8; ++nt) {                                        \
            acc[0][nt] = __builtin_amdgcn_mfma_f32_16x16x32_bf16(               \
                afr0, (BARR)[nt], acc[0][nt], 0, 0, 0);                         \
            acc[1][nt] = __builtin_amdgcn_mfma_f32_16x16x32_bf16(               \
                afr1, (BARR)[nt], acc[1][nt], 0, 0, 0);                         \
        }                                                                       \
    }

__global__ __launch_bounds__(NTHREADS)
void lstm_mfma(const int* __restrict__ x, const float* __restrict__ embWp,
               const bf16x8* __restrict__ up, float* __restrict__ out) {
    // h: bf16, double buffer, byte-swizzle ^((row&7)<<4), 1 raw barrier/step.
    // c: f32 in LDS, stride 257 (thread-private slots, no sync needed).
    __shared__ __align__(16) unsigned short hb[2][RTILE * DD];  // 32KB
    __shared__ float cb[RTILE * 257];                           // ~33KB
    __shared__ int   xs[RTILE * TSTEPS];                        // 2KB

    const int tid  = threadIdx.x;
    const int w    = tid >> 6;
    const int lane = tid & 63;
    const int l15  = lane & 15, lg = lane >> 4;
    const int base = blockIdx.x * RTILE;

    xs[tid] = x[base * TSTEPS + tid];

    f32x4 acc[2][8];          // 64 accumulator regs
    bf16x8 bA[8], bB[8];      // 32 B-frag regs, 2-deep rotation (R9-proven)

    // zero this thread's 16 c-slots
#pragma unroll
    for (int mt = 0; mt < 2; ++mt)
#pragma unroll
        for (int nn = 0; nn < 2; ++nn)
#pragma unroll
            for (int j = 0; j < 4; ++j)
                cb[(mt * 16 + lg * 4 + j) * 257 + w * 32 + nn * 16 + l15] = 0.f;

    const bf16x8* upw = up + w * 4096;    // this wave's 64KB packed U slice

    __syncthreads();   // init barrier (full drain fine here, once)

#pragma unroll 1
    for (int t = 0; t < TSTEPS; ++t) {
        // ---- acc init: z = embW[x_t] gather (+b folded), 2 float4/(mt,j) ----
#pragma unroll
        for (int mt = 0; mt < 2; ++mt) {
#pragma unroll
            for (int j = 0; j < 4; ++j) {
                const int r    = mt * 16 + lg * 4 + j;        // C/D row
                const int xrow = xs[r * TSTEPS + t];
                const float4* ew =
                    (const float4*)(embWp + ((xrow * 8 + w) * 16 + l15) * 8);
                const float4 g0 = ew[0];
                const float4 g1 = ew[1];
                acc[mt][0][j] = g0.x; acc[mt][1][j] = g0.y;
                acc[mt][2][j] = g0.z; acc[mt][3][j] = g0.w;
                acc[mt][4][j] = g1.x; acc[mt][5][j] = g1.y;
                acc[mt][6][j] = g1.z; acc[mt][7][j] = g1.w;
            }
        }

        // ---- z += h @ U via MFMA; 2-deep kt pipeline; bA(kt0) was prefetched
        //      BEFORE the previous barrier -> pipeline opens warm ----
        if (t > 0) {
            const char* rbb = (const char*)hb[(t - 1) & 1];
#pragma unroll 1
            for (int ktp = 0; ktp < 4; ++ktp) {
                const int kt0 = ktp * 2, kt1 = kt0 + 1;
                LOADB(bB, kt1)                // in queue before bA's MFMAs
                AFR_MFMA(kt0, bA)
                if (ktp < 3) { LOADB(bA, kt0 + 2) }
                AFR_MFMA(kt1, bB)
            }
        }

        // ---- prefetch next step's kt=0 B-frags (cross-barrier, in-flight) ----
        if (t < TSTEPS - 1) { LOADB(bA, 0) }

        // ---- gate update (Keras i,f,g,o; identity candidate/output) ----
        {
            char* wbb = (char*)hb[t & 1];
#pragma unroll
            for (int mt = 0; mt < 2; ++mt) {
#pragma unroll
                for (int nn = 0; nn < 2; ++nn) {
#pragma unroll
                    for (int j = 0; j < 4; ++j) {
                        const float zi = acc[mt][0 + nn][j];
                        const float zf = acc[mt][2 + nn][j];
                        const float zg = acc[mt][4 + nn][j];
                        const float zo = acc[mt][6 + nn][j];
                        const float ig = sigmoid_fast(zi);
                        const float fg = sigmoid_fast(zf);
                        const float og = sigmoid_fast(zo);
                        const int row = mt * 16 + lg * 4 + j;
                        const int d   = w * 32 + nn * 16 + l15;
                        float* cp = &cb[row * 257 + d];
                        const float cn = fg * (*cp) + ig * zg;
                        *cp = cn;
                        const float h = og * cn;
                        *(unsigned short*)(wbb +
                            ((row * 512 + d * 2) ^ ((row & 7) << 4))) = f2bf_bits(h);
                        if (t == TSTEPS - 1) out[(base + row) * DD + d] = h;
                    }
                }
            }
        }

        // ---- raw barrier: publish h(t) via LDS; do NOT drain vmcnt.
        //      Single asm (waitcnt+barrier) with memory clobber: compiler
        //      cannot move LDS ops across it; B prefetch stays in flight. ----
        asm volatile("s_waitcnt lgkmcnt(0)\n\ts_barrier" ::: "memory");
    }
}

extern "C" void kernel_launch(void* const* d_in, const int* in_sizes, int n_in,
                              void* d_out, int out_size, void* d_ws, size_t ws_size,
                              hipStream_t stream) {
    const int*   x   = (const int*)d_in[0];
    const float* emb = (const float*)d_in[1];
    const float* W   = (const float*)d_in[2];
    const float* U   = (const float*)d_in[3];
    const float* b   = (const float*)d_in[4];
    float* out = (float*)d_out;

    float*  embWp = (float*)d_ws;                          // 620KB
    bf16x8* up    = (bf16x8*)((char*)d_ws + (1 << 20));    // 512KB at +1MB

    embw_kernel<<<NCHAR, 256, 0, stream>>>(emb, W, b, embWp);
    upack_kernel<<<128, 256, 0, stream>>>(U, up);
    lstm_mfma<<<NBLOCKS, NTHREADS, 0, stream>>>(x, embWp, up, out);
}

// Round 12
// 127.359 us; speedup vs baseline: 2.9330x; 1.2130x over previous
//
#include <hip/hip_runtime.h>
#include <hip/hip_bf16.h>

// EmbeddingRNN via MFMA, round 12 = R9 chassis (144.6us best) + BYTE REDUCTION.
// R8-R11 evidence: throughput wall on the global->CU return path at ~24-29
// B/cy/CU (matches m97/m201/HK/hipBLASLt staging rates on this chip). So cut
// bytes, keep structure:
//  (1) kt=0 U-tile (64KB) LDS-resident, staged once; per-step kt0 MFMAs read
//      LDS only (conflict-free lane-linear ds_read_b128) -> -12.5% B traffic
//      and a global-independent step opening.
//  (2) kt=1 nt<3 (24KB) also LDS-resident -> -4.7%. Total LDS 157.8KB <= 160.
//  (3) embWp stored bf16 -> gather halves to 64KB/step.
// Bytes/step 640 -> 488KB. Everything else EXACT R9 (rolled 2-deep kt pipe,
// __syncthreads barrier, c-in-LDS stride 257, sigmoid via v_rcp).
// Spill-meter gate: WRITE_SIZE == 8.2MB == out.

#define DD      256
#define G4      1024
#define NCHAR   155
#define TSTEPS  16
#define RTILE   32
#define NROWS   8192
#define NBLOCKS (NROWS / RTILE)   // 256
#define NTHREADS 512              // 8 waves; wave w owns d-slice [w*32, w*32+32)

typedef __attribute__((ext_vector_type(8))) short bf16x8;
typedef __attribute__((ext_vector_type(8))) unsigned short u16x8;
typedef __attribute__((ext_vector_type(4))) float f32x4;

__device__ inline unsigned short f2bf_bits(float f) {
    __hip_bfloat16 h = __float2bfloat16(f);   // RTNE
    return *reinterpret_cast<unsigned short*>(&h);
}

__device__ inline float sigmoid_fast(float x) {
    return __builtin_amdgcn_rcpf(1.f + __expf(-x));
}

// ---------------- phase 0a: embWp8 = pack_bf16(emb @ W + b) ----------------
// value (char i, gate g, col d): w=d>>5, l15=d&15, nn=(d>>4)&1, nt=g*2+nn
// embWp8[ ((i*8 + w)*16 + l15)*8 + nt ]  (ushort bf16)
__global__ __launch_bounds__(256)
void embw_kernel(const float* __restrict__ emb, const float* __restrict__ W,
                 const float* __restrict__ b, unsigned short* __restrict__ embWp8) {
    const int i   = blockIdx.x;
    const int tid = threadIdx.x;
    float a0 = b[tid], a1 = b[256 + tid], a2 = b[512 + tid], a3 = b[768 + tid];
    const float* er = emb + i * DD;
    for (int k = 0; k < DD; ++k) {
        const float e = er[k];
        const float* wr = W + k * G4 + tid;
        a0 += e * wr[0];
        a1 += e * wr[256];
        a2 += e * wr[512];
        a3 += e * wr[768];
    }
    const int w = tid >> 5, l15 = tid & 15, nn = (tid >> 4) & 1;
    unsigned short* o = embWp8 + ((i * 8 + w) * 16 + l15) * 8 + nn;
    o[0] = f2bf_bits(a0); o[2] = f2bf_bits(a1);
    o[4] = f2bf_bits(a2); o[6] = f2bf_bits(a3);   // nt = g*2+nn
}

// ---------------- phase 0b: pack U into bf16 MFMA B-fragments ----------------
// up[((w*8 + kt)*8 + nt)*64 + lane]: lane l holds
//   U[kt*32+(l>>4)*8+j][g*256 + w*32 + nn*16 + (l&15)], nt=g*2+nn
__global__ __launch_bounds__(256)
void upack_kernel(const float* __restrict__ U, bf16x8* __restrict__ up) {
    const int gid  = blockIdx.x * 256 + threadIdx.x;   // 32768 total
    const int lane = gid & 63;
    const int nt   = (gid >> 6) & 7;
    const int kt   = (gid >> 9) & 7;
    const int w    = gid >> 12;
    const int g = nt >> 1, nn = nt & 1;
    const int col = g * 256 + w * 32 + nn * 16 + (lane & 15);
    const int k0  = kt * 32 + (lane >> 4) * 8;
    bf16x8 v;
#pragma unroll
    for (int j = 0; j < 8; ++j) v[j] = (short)f2bf_bits(U[(k0 + j) * G4 + col]);
    up[gid] = v;
}

// ---------------- phase 1: fused recurrence ----------------

#define LOADB(DST, KT)                                                          \
    _Pragma("unroll")                                                           \
    for (int nt = 0; nt < 8; ++nt) (DST)[nt] = upw[((KT) * 8 + nt) * 64 + lane];

// kt=1 global part: nt = 3..7 into DST[0..4]
#define LOADB5(DST)                                                             \
    _Pragma("unroll")                                                           \
    for (int i5 = 0; i5 < 5; ++i5) (DST)[i5] = upw[(11 + i5) * 64 + lane];

#define AFR_LOAD(KT)                                                            \
        const int kb = ((KT) * 32 + lg * 8) * 2;                                \
        const int r0 = l15, r1 = 16 + l15;                                      \
        bf16x8 afr0 = *(const bf16x8*)(rbb + ((r0 * 512 + kb) ^ ((r0 & 7) << 4))); \
        bf16x8 afr1 = *(const bf16x8*)(rbb + ((r1 * 512 + kb) ^ ((r1 & 7) << 4)));

// kt from global-loaded B regs
#define AFR_MFMA(KT, BARR)                                                      \
    {   AFR_LOAD(KT)                                                            \
        _Pragma("unroll")                                                       \
        for (int nt = 0; nt < 8; ++nt) {                                        \
            acc[0][nt] = __builtin_amdgcn_mfma_f32_16x16x32_bf16(               \
                afr0, (BARR)[nt], acc[0][nt], 0, 0, 0);                         \
            acc[1][nt] = __builtin_amdgcn_mfma_f32_16x16x32_bf16(               \
                afr1, (BARR)[nt], acc[1][nt], 0, 0, 0);                         \
        }                                                                       \
    }

// kt=0 entirely from LDS-resident tile
#define AFR_LDS0()                                                              \
    {   AFR_LOAD(0)                                                             \
        const char* bp = (const char*)BresU + w * 8192 + lane * 16;             \
        _Pragma("unroll")                                                       \
        for (int nt = 0; nt < 8; ++nt) {                                        \
            bf16x8 bf = *(const bf16x8*)(bp + nt * 1024);                       \
            acc[0][nt] = __builtin_amdgcn_mfma_f32_16x16x32_bf16(               \
                afr0, bf, acc[0][nt], 0, 0, 0);                                 \
            acc[1][nt] = __builtin_amdgcn_mfma_f32_16x16x32_bf16(               \
                afr1, bf, acc[1][nt], 0, 0, 0);                                 \
        }                                                                       \
    }

// kt=1: nt 0..2 from LDS, nt 3..7 from BARR5[0..4]
#define AFR_MIX1(BARR5)                                                         \
    {   AFR_LOAD(1)                                                             \
        const char* bp = (const char*)B1resU + w * 3072 + lane * 16;            \
        _Pragma("unroll")                                                       \
        for (int nt = 0; nt < 3; ++nt) {                                        \
            bf16x8 bf = *(const bf16x8*)(bp + nt * 1024);                       \
            acc[0][nt] = __builtin_amdgcn_mfma_f32_16x16x32_bf16(               \
                afr0, bf, acc[0][nt], 0, 0, 0);                                 \
            acc[1][nt] = __builtin_amdgcn_mfma_f32_16x16x32_bf16(               \
                afr1, bf, acc[1][nt], 0, 0, 0);                                 \
        }                                                                       \
        _Pragma("unroll")                                                       \
        for (int nt = 3; nt < 8; ++nt) {                                        \
            acc[0][nt] = __builtin_amdgcn_mfma_f32_16x16x32_bf16(               \
                afr0, (BARR5)[nt - 3], acc[0][nt], 0, 0, 0);                    \
            acc[1][nt] = __builtin_amdgcn_mfma_f32_16x16x32_bf16(               \
                afr1, (BARR5)[nt - 3], acc[1][nt], 0, 0, 0);                    \
        }                                                                       \
    }

__global__ __launch_bounds__(NTHREADS)
void lstm_mfma(const int* __restrict__ x, const unsigned short* __restrict__ embWp8,
               const bf16x8* __restrict__ up, float* __restrict__ out) {
    // h: bf16 double buffer, byte-swizzle ^((row&7)<<4); c: f32 stride 257.
    // BresU/B1resU: step-invariant U tiles (kt0 full, kt1 nt<3), staged once.
    __shared__ __align__(16) unsigned short hb[2][RTILE * DD];   // 32768 B
    __shared__ float cb[RTILE * 257];                            // 32896 B
    __shared__ int   xs[RTILE * TSTEPS];                         //  2048 B
    __shared__ __align__(16) unsigned short BresU[8 * 8 * 64 * 8];   // 65536 B
    __shared__ __align__(16) unsigned short B1resU[8 * 3 * 64 * 8];  // 24576 B

    const int tid  = threadIdx.x;
    const int w    = tid >> 6;
    const int lane = tid & 63;
    const int l15  = lane & 15, lg = lane >> 4;
    const int base = blockIdx.x * RTILE;

    xs[tid] = x[base * TSTEPS + tid];

    f32x4 acc[2][8];          // 64 accumulator regs

    // zero this thread's 16 c-slots
#pragma unroll
    for (int mt = 0; mt < 2; ++mt)
#pragma unroll
        for (int nn = 0; nn < 2; ++nn)
#pragma unroll
            for (int j = 0; j < 4; ++j)
                cb[(mt * 16 + lg * 4 + j) * 257 + w * 32 + nn * 16 + l15] = 0.f;

    const bf16x8* upw = up + w * 4096;    // this wave's 64KB packed U slice

    // ---- stage step-invariant U tiles into LDS (once) ----
    {
        char* bp = (char*)BresU + w * 8192 + lane * 16;
#pragma unroll
        for (int nt = 0; nt < 8; ++nt)
            *(bf16x8*)(bp + nt * 1024) = upw[nt * 64 + lane];         // kt=0
        char* b1 = (char*)B1resU + w * 3072 + lane * 16;
#pragma unroll
        for (int nt = 0; nt < 3; ++nt)
            *(bf16x8*)(b1 + nt * 1024) = upw[(8 + nt) * 64 + lane];   // kt=1, nt<3
    }

    __syncthreads();

#pragma unroll 1
    for (int t = 0; t < TSTEPS; ++t) {
        // ---- acc init: z = embW[x_t] gather (bf16, +b folded), 1 u16x8/(mt,j) ----
#pragma unroll
        for (int mt = 0; mt < 2; ++mt) {
#pragma unroll
            for (int j = 0; j < 4; ++j) {
                const int r    = mt * 16 + lg * 4 + j;        // C/D row
                const int xrow = xs[r * TSTEPS + t];
                const u16x8 u =
                    *(const u16x8*)(embWp8 + ((xrow * 8 + w) * 16 + l15) * 8);
#pragma unroll
                for (int gg = 0; gg < 8; ++gg)
                    acc[mt][gg][j] = __uint_as_float((unsigned)u[gg] << 16);
            }
        }

        // ---- z += h @ U via MFMA; kt0 LDS-resident, kt1 mixed, kt2..7 2-deep ----
        if (t > 0) {
            const char* rbb = (const char*)hb[(t - 1) & 1];
            bf16x8 bA[8], bB[8];
            LOADB5(bB)                        // kt1 nt3..7, fly under LDS kt0
            LOADB(bA, 2)                      // kt2, fly under kt0+kt1
            AFR_LDS0()                        // kt0: LDS only, starts instantly
            AFR_MIX1(bB)                      // kt1: 3 LDS + 5 global
#pragma unroll 1
            for (int ktp = 0; ktp < 3; ++ktp) {
                const int kt0 = 2 * ktp + 2, kt1 = kt0 + 1;   // (2,3)(4,5)(6,7)
                LOADB(bB, kt1)                // in queue before bA's MFMAs
                AFR_MFMA(kt0, bA)
                if (ktp < 2) { LOADB(bA, kt0 + 2) }
                AFR_MFMA(kt1, bB)
            }
        }

        // ---- gate update (Keras i,f,g,o; identity candidate/output) ----
        {
            char* wbb = (char*)hb[t & 1];
#pragma unroll
            for (int mt = 0; mt < 2; ++mt) {
#pragma unroll
                for (int nn = 0; nn < 2; ++nn) {
#pragma unroll
                    for (int j = 0; j < 4; ++j) {
                        const float zi = acc[mt][0 + nn][j];
                        const float zf = acc[mt][2 + nn][j];
                        const float zg = acc[mt][4 + nn][j];
                        const float zo = acc[mt][6 + nn][j];
                        const float ig = sigmoid_fast(zi);
                        const float fg = sigmoid_fast(zf);
                        const float og = sigmoid_fast(zo);
                        const int row = mt * 16 + lg * 4 + j;
                        const int d   = w * 32 + nn * 16 + l15;
                        float* cp = &cb[row * 257 + d];
                        const float cn = fg * (*cp) + ig * zg;
                        *cp = cn;
                        const float h = og * cn;
                        *(unsigned short*)(wbb +
                            ((row * 512 + d * 2) ^ ((row & 7) << 4))) = f2bf_bits(h);
                        if (t == TSTEPS - 1) out[(base + row) * DD + d] = h;
                    }
                }
            }
        }
        __syncthreads();   // publish h(t); prev-buffer reads done
    }
}

extern "C" void kernel_launch(void* const* d_in, const int* in_sizes, int n_in,
                              void* d_out, int out_size, void* d_ws, size_t ws_size,
                              hipStream_t stream) {
    const int*   x   = (const int*)d_in[0];
    const float* emb = (const float*)d_in[1];
    const float* W   = (const float*)d_in[2];
    const float* U   = (const float*)d_in[3];
    const float* b   = (const float*)d_in[4];
    float* out = (float*)d_out;

    unsigned short* embWp8 = (unsigned short*)d_ws;        // 155*1024*2 = 317KB
    bf16x8*         up     = (bf16x8*)((char*)d_ws + (1 << 20));   // 512KB at +1MB

    embw_kernel<<<NCHAR, 256, 0, stream>>>(emb, W, b, embWp8);
    upack_kernel<<<128, 256, 0, stream>>>(U, up);
    lstm_mfma<<<NBLOCKS, NTHREADS, 0, stream>>>(x, embWp8, up, out);
}